// Round 11
// baseline (634.722 us; speedup 1.0000x reference)
//
#include <hip/hip_runtime.h>
#include <hip/hip_bf16.h>

#define NN 50000
#define NE 800000
#define D 128
#define ED 64
#define IN_DIM 320
#define MB 64            // edges per tile
#define KP 328           // padded LDS row (ushorts)
#define NT (NE / MB)     // 12500 tiles
#define PGRID 512        // 2 blocks/CU * 256 CU — tripwire-passing config
#define NB ((NN + 255) / 256)   // 196 scan blocks

typedef short short8 __attribute__((ext_vector_type(8)));
typedef float f32x4 __attribute__((ext_vector_type(4)));

__device__ __forceinline__ ushort f2b(float f) {
  __hip_bfloat16 h = __float2bfloat16(f);
  return *reinterpret_cast<ushort*>(&h);
}
__device__ __forceinline__ float b2f(ushort u) {
  return __uint_as_float(((uint)u) << 16);
}
__device__ __forceinline__ ushort4 c4(float4 v) {
  ushort4 u; u.x = f2b(v.x); u.y = f2b(v.y); u.z = f2b(v.z); u.w = f2b(v.w);
  return u;
}

// gather one tile's x into bf16 registers; 4 threads per edge, 20 x ushort4
__device__ __forceinline__ void gather_regs(
    ushort4 g[20], const int* __restrict__ senders,
    const int* __restrict__ receivers, const float* __restrict__ nodes,
    const float* __restrict__ efeat, int e0, int tid)
{
  const int e = tid >> 2, p = tid & 3;
  const float* ns = nodes + (size_t)senders[e0 + e] * D;
  const float* nr = nodes + (size_t)receivers[e0 + e] * D;
  const float* ef = efeat + (size_t)(e0 + e) * ED;
#pragma unroll
  for (int i = 0; i < 8; ++i) g[i] = c4(*(const float4*)(ns + (p + 4 * i) * 4));
#pragma unroll
  for (int i = 0; i < 8; ++i) g[8 + i] = c4(*(const float4*)(nr + (p + 4 * i) * 4));
#pragma unroll
  for (int i = 0; i < 4; ++i) g[16 + i] = c4(*(const float4*)(ef + (p + 4 * i) * 4));
}

__device__ __forceinline__ void write_xs(
    ushort xs[MB][KP], const ushort4 g[20], int tid)
{
  const int e = tid >> 2, p = tid & 3;
#pragma unroll
  for (int i = 0; i < 8; ++i)
    *reinterpret_cast<ushort4*>(&xs[e][(p + 4 * i) * 4]) = g[i];
#pragma unroll
  for (int i = 0; i < 8; ++i)
    *reinterpret_cast<ushort4*>(&xs[e][128 + (p + 4 * i) * 4]) = g[8 + i];
#pragma unroll
  for (int i = 0; i < 4; ++i)
    *reinterpret_cast<ushort4*>(&xs[e][256 + (p + 4 * i) * 4]) = g[16 + i];
}

// ---------------- weight transpose + bf16 convert ---------------------------
__global__ __launch_bounds__(256) void k_wconv(
    const float* __restrict__ Wq, const float* __restrict__ W1,
    ushort* __restrict__ Wqt, ushort* __restrict__ W1t)
{
  int i = blockIdx.x * 256 + threadIdx.x;
  if (i < D * IN_DIM) {
    int n = i / IN_DIM, k = i - n * IN_DIM;
    Wqt[i] = f2b(Wq[k * D + n]);
    W1t[i] = f2b(W1[k * D + n]);
  }
}

// ---------------- pass 1: queries (bf16, bucket-permuted) + logits + max ----
// Single fused GEMM pass: each A fragment read once, both weight matrices
// streamed from L2 with ALL weight loads issued BEFORE the prefetch gathers
// (round-3 lesson: a weight load issued after the gathers makes every
// weight-consume vmcnt-wait drain the whole gather queue). queries/logits
// are written at pos[e] (bucket order) so k_out streams sequentially.
__global__ __launch_bounds__(256, 2) void k_fused(
    const float* __restrict__ nodes,
    const int* __restrict__ senders, const int* __restrict__ receivers,
    const float* __restrict__ efeat,
    const ushort* __restrict__ Wqt, const float* __restrict__ bq,
    const ushort* __restrict__ W1t, const float* __restrict__ b1,
    const float* __restrict__ gamma_, const float* __restrict__ beta_,
    const float* __restrict__ W2, const float* __restrict__ b2,
    const int* __restrict__ pos,
    ushort* __restrict__ queries, float* __restrict__ lgp,
    float* __restrict__ seg_max)
{
  __shared__ ushort xs[MB][KP];
  __shared__ float red[MB][4][3];
  __shared__ int pos_s[MB];
  const int tid = threadIdx.x;
  const int w = tid >> 6, l = tid & 63, lr = l & 15, lg = l >> 4;
  const int n0 = 32 * w + lr, n1 = 32 * w + 16 + lr;

  const float b1a = b1[n0], b1b = b1[n1];
  const float g0 = gamma_[n0], g1 = gamma_[n1];
  const float be0 = beta_[n0], be1 = beta_[n1];
  const float w20 = W2[n0], w21 = W2[n1];
  const float bq0 = bq[n0], bq1 = bq[n1];
  const float b2s = b2[0];
  const float wg0 = w20 * g0, wg1 = w21 * g1;

  // tile-invariant: S1=sum(w2*g), B2t=sum(w2*beta)+b2 (0.25: cols counted 4x)
  {
    float p1 = wg0 + wg1;
    float p2 = w20 * be0 + w21 * be1;
#pragma unroll
    for (int off = 1; off < 64; off <<= 1) {
      p1 += __shfl_xor(p1, off);
      p2 += __shfl_xor(p2, off);
    }
    if (l == 0) { red[0][w][0] = p1; red[0][w][1] = p2; }
  }
  __syncthreads();
  const float S1  = 0.25f * (red[0][0][0] + red[0][1][0] + red[0][2][0] + red[0][3][0]);
  const float B2t = 0.25f * (red[0][0][1] + red[0][1][1] + red[0][2][1] + red[0][3][1]) + b2s;

  int tile = blockIdx.x;
  ushort4 g[20];
  gather_regs(g, senders, receivers, nodes, efeat, tile * MB, tid);

  while (tile < NT) {
    const int e0 = tile * MB;
    // pos_s: read between sync(A) and sync(B) only; rewritten here after
    // sync(B) of the previous iteration -> single buffer is race-free.
    if (tid < MB) pos_s[tid] = pos[e0 + tid];
    write_xs(xs, g, tid);
    __syncthreads();                                   // (A) xs + pos_s ready

    // ---- fused GEMM: A read once; Wq+W1 streamed (before any gathers)
    f32x4 aq[4][2] = {};
    f32x4 ah[4][2] = {};
#pragma unroll 2
    for (int ks = 0; ks < 10; ++ks) {
      short8 Q0 = *reinterpret_cast<const short8*>(Wqt + n0 * IN_DIM + ks * 32 + lg * 8);
      short8 Q1 = *reinterpret_cast<const short8*>(Wqt + n1 * IN_DIM + ks * 32 + lg * 8);
      short8 Y0 = *reinterpret_cast<const short8*>(W1t + n0 * IN_DIM + ks * 32 + lg * 8);
      short8 Y1 = *reinterpret_cast<const short8*>(W1t + n1 * IN_DIM + ks * 32 + lg * 8);
      short8 A[4];
#pragma unroll
      for (int mt = 0; mt < 4; ++mt)
        A[mt] = *reinterpret_cast<const short8*>(&xs[mt * 16 + lr][ks * 32 + lg * 8]);
#pragma unroll
      for (int mt = 0; mt < 4; ++mt) {
        aq[mt][0] = __builtin_amdgcn_mfma_f32_16x16x32_bf16(A[mt], Q0, aq[mt][0], 0, 0, 0);
        aq[mt][1] = __builtin_amdgcn_mfma_f32_16x16x32_bf16(A[mt], Q1, aq[mt][1], 0, 0, 0);
        ah[mt][0] = __builtin_amdgcn_mfma_f32_16x16x32_bf16(A[mt], Y0, ah[mt][0], 0, 0, 0);
        ah[mt][1] = __builtin_amdgcn_mfma_f32_16x16x32_bf16(A[mt], Y1, ah[mt][1], 0, 0, 0);
      }
    }

    // ---- store queries (+bq) at permuted rows (bucket order)
#pragma unroll
    for (int mt = 0; mt < 4; ++mt)
#pragma unroll
      for (int r = 0; r < 4; ++r) {
        int row = mt * 16 + lg * 4 + r;
        int p = pos_s[row];
        queries[(size_t)p * D + n0] = f2b(aq[mt][0][r] + bq0);
        queries[(size_t)p * D + n1] = f2b(aq[mt][1][r] + bq1);
      }

    // ---- prefetch next tile's gathers (all weight loads already issued;
    //      latency covered by partials + epilogue + next write_xs wait)
    const int nxt = tile + PGRID;
    if (nxt < NT)
      gather_regs(g, senders, receivers, nodes, efeat, nxt * MB, tid);

    // ---- relu + fused LN/dot partials (16-lane reduce)
#pragma unroll
    for (int mt = 0; mt < 4; ++mt)
#pragma unroll
      for (int r = 0; r < 4; ++r) {
        float h0 = fmaxf(ah[mt][0][r] + b1a, 0.f);
        float h1 = fmaxf(ah[mt][1][r] + b1b, 0.f);
        float s = h0 + h1;
        float q = h0 * h0 + h1 * h1;
        float t = h0 * wg0 + h1 * wg1;
#pragma unroll
        for (int off = 1; off < 16; off <<= 1) {
          s += __shfl_xor(s, off);
          q += __shfl_xor(q, off);
          t += __shfl_xor(t, off);
        }
        if (lr == mt * 4 + r) {
          int row = mt * 16 + lg * 4 + r;
          red[row][w][0] = s;
          red[row][w][1] = q;
          red[row][w][2] = t;
        }
      }
    __syncthreads();                                   // (B) red ready
    if (tid < MB) {
      float s = red[tid][0][0] + red[tid][1][0] + red[tid][2][0] + red[tid][3][0];
      float q = red[tid][0][1] + red[tid][1][1] + red[tid][2][1] + red[tid][3][1];
      float t = red[tid][0][2] + red[tid][1][2] + red[tid][2][2] + red[tid][3][2];
      float mu = s * (1.f / 128.f);
      float var = fmaxf(q * (1.f / 128.f) - mu * mu, 0.f);
      float rs = rsqrtf(var + 1e-5f);
      float logit = fmaxf(rs * (t - mu * S1) + B2t, 0.f);
      lgp[pos[e0 + tid]] = logit;        // global pos read (not pos_s: epilogue
                                         // runs after sync(B), pos_s may be
                                         // rewritten by other waves' loop-top)
      atomicMax((int*)&seg_max[receivers[e0 + tid]], __float_as_int(logit));
    }
    tile = nxt;
  }
}

// ---------------- counting sort by receiver ---------------------------------
__global__ __launch_bounds__(256) void k_hist(
    const int* __restrict__ receivers, int* __restrict__ deg)
{
  int e = blockIdx.x * 256 + threadIdx.x;
  if (e < NE) atomicAdd(&deg[receivers[e]], 1);
}

__global__ __launch_bounds__(256) void k_scan1(
    const int* __restrict__ deg, int* __restrict__ bsum)
{
  __shared__ int buf[256];
  int i = blockIdx.x * 256 + threadIdx.x;
  int v = (i < NN) ? deg[i] : 0;
  buf[threadIdx.x] = v;
  __syncthreads();
  for (int off = 128; off > 0; off >>= 1) {
    if (threadIdx.x < off) buf[threadIdx.x] += buf[threadIdx.x + off];
    __syncthreads();
  }
  if (threadIdx.x == 0) bsum[blockIdx.x] = buf[0];
}

__global__ __launch_bounds__(256) void k_scan2(
    const int* __restrict__ bsum, int* __restrict__ bpre, int* __restrict__ offs)
{
  __shared__ int buf[256];
  int t = threadIdx.x;
  int v = (t < NB) ? bsum[t] : 0;
  buf[t] = v;
  __syncthreads();
  for (int off = 1; off < 256; off <<= 1) {
    int x = (t >= off) ? buf[t - off] : 0;
    __syncthreads();
    buf[t] += x;
    __syncthreads();
  }
  if (t < NB) bpre[t] = buf[t] - v;          // exclusive
  if (t == 0) offs[NN] = NE;                  // sentinel
}

__global__ __launch_bounds__(256) void k_scan3(
    const int* __restrict__ deg, const int* __restrict__ bpre,
    int* __restrict__ offs, int* __restrict__ cursor)
{
  __shared__ int buf[256];
  int t = threadIdx.x;
  int i = blockIdx.x * 256 + t;
  int v = (i < NN) ? deg[i] : 0;
  buf[t] = v;
  __syncthreads();
  for (int off = 1; off < 256; off <<= 1) {
    int x = (t >= off) ? buf[t - off] : 0;
    __syncthreads();
    buf[t] += x;
    __syncthreads();
  }
  if (i < NN) {
    int o = bpre[blockIdx.x] + buf[t] - v;
    offs[i] = o;
    cursor[i] = o;
  }
}

__global__ __launch_bounds__(256) void k_bucket(
    const int* __restrict__ receivers, int* __restrict__ cursor,
    int* __restrict__ ebuf)
{
  int e = blockIdx.x * 256 + threadIdx.x;
  if (e < NE) {
    int pos = atomicAdd(&cursor[receivers[e]], 1);
    ebuf[pos] = e;
  }
}

// Canonicalize bucket order (atomicAdd placement is scheduling-dependent):
// insertion-sort each node's segment so ebuf is a pure function of inputs.
__global__ __launch_bounds__(256) void k_bsort(
    const int* __restrict__ offs, int* __restrict__ ebuf)
{
  int node = blockIdx.x * 256 + threadIdx.x;
  if (node >= NN) return;
  const int beg = offs[node], end = offs[node + 1];
  for (int i = beg + 1; i < end; ++i) {
    int v = ebuf[i];
    int j = i - 1;
    while (j >= beg && ebuf[j] > v) { ebuf[j + 1] = ebuf[j]; --j; }
    ebuf[j + 1] = v;
  }
}

// inverse permutation: pos[e] = position of edge e in sorted bucket layout
__global__ __launch_bounds__(256) void k_pos(
    const int* __restrict__ ebuf, int* __restrict__ pos)
{
  int i = blockIdx.x * 256 + threadIdx.x;
  if (i < NE) pos[ebuf[i]] = i;
}

// ---------------- gather-side output: one wave per node, streaming reads ----
// queries/lgp are in bucket order -> rows beg..end are contiguous.
__global__ __launch_bounds__(256) void k_out(
    const int* __restrict__ offs, const float* __restrict__ lgp,
    const float* __restrict__ seg_max, const ushort* __restrict__ queries,
    float* __restrict__ out)
{
  int node = blockIdx.x * 4 + (threadIdx.x >> 6);
  if (node >= NN) return;
  const int l = threadIdx.x & 63;
  const int beg = offs[node], end = offs[node + 1];
  const float smax = seg_max[node];
  float a0 = 0.f, a1 = 0.f, den = 0.f;
  for (int i = beg; i < end; ++i) {
    float ex = expf(lgp[i] - smax);
    ushort2 q = *reinterpret_cast<const ushort2*>(queries + (size_t)i * D + 2 * l);
    a0 = fmaf(ex, b2f(q.x), a0);
    a1 = fmaf(ex, b2f(q.y), a1);
    den += ex;
  }
  float inv = 1.f / (den + 1e-10f);
  float v0 = a0 * inv, v1 = a1 * inv;
  v0 = v0 > 0.f ? v0 : 0.01f * v0;
  v1 = v1 > 0.f ? v1 : 0.01f * v1;
  *reinterpret_cast<float2*>(out + (size_t)node * D + 2 * l) = make_float2(v0, v1);
}

extern "C" void kernel_launch(void* const* d_in, const int* in_sizes, int n_in,
                              void* d_out, int out_size, void* d_ws, size_t ws_size,
                              hipStream_t stream) {
  const float* nodes  = (const float*)d_in[0];
  const int*   eidx   = (const int*)d_in[1];
  const float* efeat  = (const float*)d_in[2];
  const float* Wq     = (const float*)d_in[3];
  const float* bq     = (const float*)d_in[4];
  const float* W1     = (const float*)d_in[5];
  const float* b1     = (const float*)d_in[6];
  const float* gamma_ = (const float*)d_in[7];
  const float* beta_  = (const float*)d_in[8];
  const float* W2     = (const float*)d_in[9];
  const float* b2     = (const float*)d_in[10];
  const int* senders   = eidx;
  const int* receivers = eidx + NE;

  // ws layout (pad before ebuf keeps Wqt/W1t/queries 16B-aligned)
  float* ws       = (float*)d_ws;
  float* lgp      = ws;                      // NE f32 (bucket-ordered logits)
  float* seg_max  = ws + NE;                 // NN f32
  int*   deg      = (int*)(seg_max + NN);    // NN
  int*   offs     = deg + NN;                // NN+1
  int*   cursor   = offs + NN + 1;           // NN
  int*   bsum     = cursor + NN;             // 256
  int*   bpre     = bsum + 256;              // 256
  int*   ebuf     = bpre + 256 + 3;          // NE
  int*   pos      = ebuf + NE;               // NE
  ushort* Wqt     = (ushort*)(pos + NE);     // 128*320, 16B-aligned
  ushort* W1t     = Wqt + D * IN_DIM;        // 128*320, 16B-aligned
  ushort* queries = W1t + D * IN_DIM;        // NE*128 bf16 (bucket-ordered)

  hipMemsetAsync(seg_max, 0, NN * sizeof(float), stream);
  hipMemsetAsync(deg, 0, NN * sizeof(int), stream);

  k_wconv<<<(D * IN_DIM + 255) / 256, 256, 0, stream>>>(Wq, W1, Wqt, W1t);

  // counting sort + canonical order + inverse permutation
  k_hist<<<(NE + 255) / 256, 256, 0, stream>>>(receivers, deg);
  k_scan1<<<NB, 256, 0, stream>>>(deg, bsum);
  k_scan2<<<1, 256, 0, stream>>>(bsum, bpre, offs);
  k_scan3<<<NB, 256, 0, stream>>>(deg, bpre, offs, cursor);
  k_bucket<<<(NE + 255) / 256, 256, 0, stream>>>(receivers, cursor, ebuf);
  k_bsort<<<NB, 256, 0, stream>>>(offs, ebuf);
  k_pos<<<(NE + 255) / 256, 256, 0, stream>>>(ebuf, pos);

  // queries (permuted) + logits (permuted) + seg_max
  k_fused<<<PGRID, 256, 0, stream>>>(nodes, senders, receivers, efeat,
                                     Wqt, bq, W1t, b1, gamma_, beta_, W2, b2,
                                     pos, queries, lgp, seg_max);

  // gather-side softmax + weighted sum + leaky relu (streaming)
  k_out<<<(NN + 3) / 4, 256, 0, stream>>>(offs, lgp, seg_max,
                                          queries, (float*)d_out);
}

// Round 12
// 527.638 us; speedup vs baseline: 1.2029x; 1.2029x over previous
//
#include <hip/hip_runtime.h>
#include <hip/hip_bf16.h>

#define NN 50000
#define NE 800000
#define D 128
#define ED 64
#define IN_DIM 320
#define MB 64            // edges per tile
#define KP 328           // padded LDS row (ushorts)
#define NT (NE / MB)     // 12500 tiles
#define PGRID 512        // 2 blocks/CU * 256 CU — tripwire-passing config
#define NB ((NN + 255) / 256)   // 196 scan blocks

typedef short short8 __attribute__((ext_vector_type(8)));
typedef float f32x4 __attribute__((ext_vector_type(4)));

__device__ __forceinline__ ushort f2b(float f) {
  __hip_bfloat16 h = __float2bfloat16(f);
  return *reinterpret_cast<ushort*>(&h);
}
__device__ __forceinline__ float b2f(ushort u) {
  return __uint_as_float(((uint)u) << 16);
}
__device__ __forceinline__ ushort4 c4(float4 v) {
  ushort4 u; u.x = f2b(v.x); u.y = f2b(v.y); u.z = f2b(v.z); u.w = f2b(v.w);
  return u;
}

// gather one tile's x into bf16 registers; 4 threads per edge, 20 x ushort4
__device__ __forceinline__ void gather_regs(
    ushort4 g[20], const int* __restrict__ senders,
    const int* __restrict__ receivers, const float* __restrict__ nodes,
    const float* __restrict__ efeat, int e0, int tid)
{
  const int e = tid >> 2, p = tid & 3;
  const float* ns = nodes + (size_t)senders[e0 + e] * D;
  const float* nr = nodes + (size_t)receivers[e0 + e] * D;
  const float* ef = efeat + (size_t)(e0 + e) * ED;
#pragma unroll
  for (int i = 0; i < 8; ++i) g[i] = c4(*(const float4*)(ns + (p + 4 * i) * 4));
#pragma unroll
  for (int i = 0; i < 8; ++i) g[8 + i] = c4(*(const float4*)(nr + (p + 4 * i) * 4));
#pragma unroll
  for (int i = 0; i < 4; ++i) g[16 + i] = c4(*(const float4*)(ef + (p + 4 * i) * 4));
}

__device__ __forceinline__ void write_xs(
    ushort xs[MB][KP], const ushort4 g[20], int tid)
{
  const int e = tid >> 2, p = tid & 3;
#pragma unroll
  for (int i = 0; i < 8; ++i)
    *reinterpret_cast<ushort4*>(&xs[e][(p + 4 * i) * 4]) = g[i];
#pragma unroll
  for (int i = 0; i < 8; ++i)
    *reinterpret_cast<ushort4*>(&xs[e][128 + (p + 4 * i) * 4]) = g[8 + i];
#pragma unroll
  for (int i = 0; i < 4; ++i)
    *reinterpret_cast<ushort4*>(&xs[e][256 + (p + 4 * i) * 4]) = g[16 + i];
}

// ---------------- weight transpose + bf16 convert ---------------------------
__global__ __launch_bounds__(256) void k_wconv(
    const float* __restrict__ Wq, const float* __restrict__ W1,
    ushort* __restrict__ Wqt, ushort* __restrict__ W1t)
{
  int i = blockIdx.x * 256 + threadIdx.x;
  if (i < D * IN_DIM) {
    int n = i / IN_DIM, k = i - n * IN_DIM;
    Wqt[i] = f2b(Wq[k * D + n]);
    W1t[i] = f2b(W1[k * D + n]);
  }
}

// ---------------- pass 1: queries (bf16,+bq) + logits + seg_max -------------
// EXACT round-10 kernel (348us, tripwire-green). Round-11's fused single-pass
// + permuted stores regressed to 451us (register pressure + scattered writes);
// reverted.
__global__ __launch_bounds__(256, 2) void k_fused(
    const float* __restrict__ nodes,
    const int* __restrict__ senders, const int* __restrict__ receivers,
    const float* __restrict__ efeat,
    const ushort* __restrict__ Wqt, const float* __restrict__ bq,
    const ushort* __restrict__ W1t, const float* __restrict__ b1,
    const float* __restrict__ gamma_, const float* __restrict__ beta_,
    const float* __restrict__ W2, const float* __restrict__ b2,
    ushort* __restrict__ queries, float* __restrict__ logits,
    float* __restrict__ seg_max)
{
  __shared__ ushort xs[MB][KP];
  __shared__ float red[MB][4][3];
  const int tid = threadIdx.x;
  const int w = tid >> 6, l = tid & 63, lr = l & 15, lg = l >> 4;
  const int n0 = 32 * w + lr, n1 = 32 * w + 16 + lr;

  const float b1a = b1[n0], b1b = b1[n1];
  const float g0 = gamma_[n0], g1 = gamma_[n1];
  const float be0 = beta_[n0], be1 = beta_[n1];
  const float w20 = W2[n0], w21 = W2[n1];
  const float bq0 = bq[n0], bq1 = bq[n1];
  const float b2s = b2[0];
  const float wg0 = w20 * g0, wg1 = w21 * g1;

  // tile-invariant: S1=sum(w2*g), B2t=sum(w2*beta)+b2 (0.25: cols counted 4x)
  {
    float p1 = wg0 + wg1;
    float p2 = w20 * be0 + w21 * be1;
#pragma unroll
    for (int off = 1; off < 64; off <<= 1) {
      p1 += __shfl_xor(p1, off);
      p2 += __shfl_xor(p2, off);
    }
    if (l == 0) { red[0][w][0] = p1; red[0][w][1] = p2; }
  }
  __syncthreads();
  const float S1  = 0.25f * (red[0][0][0] + red[0][1][0] + red[0][2][0] + red[0][3][0]);
  const float B2t = 0.25f * (red[0][0][1] + red[0][1][1] + red[0][2][1] + red[0][3][1]) + b2s;

  int tile = blockIdx.x;
  ushort4 g[20];
  gather_regs(g, senders, receivers, nodes, efeat, tile * MB, tid);

  while (tile < NT) {
    const int e0 = tile * MB;
    write_xs(xs, g, tid);
    __syncthreads();                                   // (A) xs ready

    // q-GEMM: Wq streamed from L2 (issued BEFORE prefetch gathers)
    f32x4 aq[4][2] = {};
#pragma unroll 2
    for (int ks = 0; ks < 10; ++ks) {
      short8 Q0 = *reinterpret_cast<const short8*>(Wqt + n0 * IN_DIM + ks * 32 + lg * 8);
      short8 Q1 = *reinterpret_cast<const short8*>(Wqt + n1 * IN_DIM + ks * 32 + lg * 8);
      short8 A[4];
#pragma unroll
      for (int mt = 0; mt < 4; ++mt)
        A[mt] = *reinterpret_cast<const short8*>(&xs[mt * 16 + lr][ks * 32 + lg * 8]);
#pragma unroll
      for (int mt = 0; mt < 4; ++mt) {
        aq[mt][0] = __builtin_amdgcn_mfma_f32_16x16x32_bf16(A[mt], Q0, aq[mt][0], 0, 0, 0);
        aq[mt][1] = __builtin_amdgcn_mfma_f32_16x16x32_bf16(A[mt], Q1, aq[mt][1], 0, 0, 0);
      }
    }
#pragma unroll
    for (int mt = 0; mt < 4; ++mt)
#pragma unroll
      for (int r = 0; r < 4; ++r) {
        int row = mt * 16 + lg * 4 + r;
        queries[(size_t)(e0 + row) * D + n0] = f2b(aq[mt][0][r] + bq0);
        queries[(size_t)(e0 + row) * D + n1] = f2b(aq[mt][1][r] + bq1);
      }

    // prefetch next tile's gathers
    const int nxt = tile + PGRID;
    if (nxt < NT)
      gather_regs(g, senders, receivers, nodes, efeat, nxt * MB, tid);

    // h-GEMM: weights streamed again (round-11 showed this beats fusing)
    f32x4 ah[4][2] = {};
#pragma unroll
    for (int ks = 0; ks < 10; ++ks) {
      short8 Y0 = *reinterpret_cast<const short8*>(W1t + n0 * IN_DIM + ks * 32 + lg * 8);
      short8 Y1 = *reinterpret_cast<const short8*>(W1t + n1 * IN_DIM + ks * 32 + lg * 8);
      short8 A[4];
#pragma unroll
      for (int mt = 0; mt < 4; ++mt)
        A[mt] = *reinterpret_cast<const short8*>(&xs[mt * 16 + lr][ks * 32 + lg * 8]);
#pragma unroll
      for (int mt = 0; mt < 4; ++mt) {
        ah[mt][0] = __builtin_amdgcn_mfma_f32_16x16x32_bf16(A[mt], Y0, ah[mt][0], 0, 0, 0);
        ah[mt][1] = __builtin_amdgcn_mfma_f32_16x16x32_bf16(A[mt], Y1, ah[mt][1], 0, 0, 0);
      }
    }

    // relu + fused LN/dot partials (16-lane reduce: each col once per group)
#pragma unroll
    for (int mt = 0; mt < 4; ++mt)
#pragma unroll
      for (int r = 0; r < 4; ++r) {
        float h0 = fmaxf(ah[mt][0][r] + b1a, 0.f);
        float h1 = fmaxf(ah[mt][1][r] + b1b, 0.f);
        float s = h0 + h1;
        float q = h0 * h0 + h1 * h1;
        float t = h0 * wg0 + h1 * wg1;
#pragma unroll
        for (int off = 1; off < 16; off <<= 1) {
          s += __shfl_xor(s, off);
          q += __shfl_xor(q, off);
          t += __shfl_xor(t, off);
        }
        if (lr == mt * 4 + r) {
          int row = mt * 16 + lg * 4 + r;
          red[row][w][0] = s;
          red[row][w][1] = q;
          red[row][w][2] = t;
        }
      }
    __syncthreads();                                   // (B) red ready
    if (tid < MB) {
      float s = red[tid][0][0] + red[tid][1][0] + red[tid][2][0] + red[tid][3][0];
      float q = red[tid][0][1] + red[tid][1][1] + red[tid][2][1] + red[tid][3][1];
      float t = red[tid][0][2] + red[tid][1][2] + red[tid][2][2] + red[tid][3][2];
      float mu = s * (1.f / 128.f);
      float var = fmaxf(q * (1.f / 128.f) - mu * mu, 0.f);
      float rs = rsqrtf(var + 1e-5f);
      float logit = fmaxf(rs * (t - mu * S1) + B2t, 0.f);
      logits[e0 + tid] = logit;
      atomicMax((int*)&seg_max[receivers[e0 + tid]], __float_as_int(logit));
    }
    tile = nxt;
  }
}

// ---------------- counting sort by receiver ---------------------------------
__global__ __launch_bounds__(256) void k_hist(
    const int* __restrict__ receivers, int* __restrict__ deg)
{
  int e = blockIdx.x * 256 + threadIdx.x;
  if (e < NE) atomicAdd(&deg[receivers[e]], 1);
}

__global__ __launch_bounds__(256) void k_scan1(
    const int* __restrict__ deg, int* __restrict__ bsum)
{
  __shared__ int buf[256];
  int i = blockIdx.x * 256 + threadIdx.x;
  int v = (i < NN) ? deg[i] : 0;
  buf[threadIdx.x] = v;
  __syncthreads();
  for (int off = 128; off > 0; off >>= 1) {
    if (threadIdx.x < off) buf[threadIdx.x] += buf[threadIdx.x + off];
    __syncthreads();
  }
  if (threadIdx.x == 0) bsum[blockIdx.x] = buf[0];
}

__global__ __launch_bounds__(256) void k_scan2(
    const int* __restrict__ bsum, int* __restrict__ bpre, int* __restrict__ offs)
{
  __shared__ int buf[256];
  int t = threadIdx.x;
  int v = (t < NB) ? bsum[t] : 0;
  buf[t] = v;
  __syncthreads();
  for (int off = 1; off < 256; off <<= 1) {
    int x = (t >= off) ? buf[t - off] : 0;
    __syncthreads();
    buf[t] += x;
    __syncthreads();
  }
  if (t < NB) bpre[t] = buf[t] - v;          // exclusive
  if (t == 0) offs[NN] = NE;                  // sentinel
}

__global__ __launch_bounds__(256) void k_scan3(
    const int* __restrict__ deg, const int* __restrict__ bpre,
    int* __restrict__ offs, int* __restrict__ cursor)
{
  __shared__ int buf[256];
  int t = threadIdx.x;
  int i = blockIdx.x * 256 + t;
  int v = (i < NN) ? deg[i] : 0;
  buf[t] = v;
  __syncthreads();
  for (int off = 1; off < 256; off <<= 1) {
    int x = (t >= off) ? buf[t - off] : 0;
    __syncthreads();
    buf[t] += x;
    __syncthreads();
  }
  if (i < NN) {
    int o = bpre[blockIdx.x] + buf[t] - v;
    offs[i] = o;
    cursor[i] = o;
  }
}

__global__ __launch_bounds__(256) void k_bucket(
    const int* __restrict__ receivers, int* __restrict__ cursor,
    int* __restrict__ ebuf)
{
  int e = blockIdx.x * 256 + threadIdx.x;
  if (e < NE) {
    int pos = atomicAdd(&cursor[receivers[e]], 1);
    ebuf[pos] = e;
  }
}

// Canonicalize bucket order (atomicAdd placement is scheduling-dependent):
// insertion-sort each node's segment so ebuf is a pure function of inputs.
__global__ __launch_bounds__(256) void k_bsort(
    const int* __restrict__ offs, int* __restrict__ ebuf)
{
  int node = blockIdx.x * 256 + threadIdx.x;
  if (node >= NN) return;
  const int beg = offs[node], end = offs[node + 1];
  for (int i = beg + 1; i < end; ++i) {
    int v = ebuf[i];
    int j = i - 1;
    while (j >= beg && ebuf[j] > v) { ebuf[j + 1] = ebuf[j]; --j; }
    ebuf[j + 1] = v;
  }
}

// ---------------- gather-side output ----------------------------------------
// 2 nodes per wave (32 lanes x ushort4 = full 256B row per half-wave, no
// cross-lane combine) + 4-deep load batching. Accumulation per column stays
// STRICTLY in ascending-i order -> bit-identical to the round-10 k_out per
// node (tripwire-safe), but with ~4x the memory-level parallelism.
__global__ __launch_bounds__(256) void k_out(
    const int* __restrict__ offs, const int* __restrict__ ebuf,
    const float* __restrict__ logits, const float* __restrict__ seg_max,
    const ushort* __restrict__ queries, float* __restrict__ out)
{
  int node = blockIdx.x * 8 + (threadIdx.x >> 5);
  if (node >= NN) return;
  const int cg = (threadIdx.x & 31) * 4;      // 4 columns per lane
  const int beg = offs[node], end = offs[node + 1];
  const float smax = seg_max[node];
  float a0 = 0.f, a1 = 0.f, a2 = 0.f, a3 = 0.f, den = 0.f;

  int i = beg;
  for (; i + 4 <= end; i += 4) {
    int e0 = ebuf[i], e1 = ebuf[i + 1], e2 = ebuf[i + 2], e3 = ebuf[i + 3];
    float l0 = logits[e0], l1 = logits[e1], l2 = logits[e2], l3 = logits[e3];
    ushort4 q0 = *reinterpret_cast<const ushort4*>(queries + (size_t)e0 * D + cg);
    ushort4 q1 = *reinterpret_cast<const ushort4*>(queries + (size_t)e1 * D + cg);
    ushort4 q2 = *reinterpret_cast<const ushort4*>(queries + (size_t)e2 * D + cg);
    ushort4 q3 = *reinterpret_cast<const ushort4*>(queries + (size_t)e3 * D + cg);
    float x0 = expf(l0 - smax), x1 = expf(l1 - smax);
    float x2 = expf(l2 - smax), x3 = expf(l3 - smax);
    a0 = fmaf(x0, b2f(q0.x), a0); a1 = fmaf(x0, b2f(q0.y), a1);
    a2 = fmaf(x0, b2f(q0.z), a2); a3 = fmaf(x0, b2f(q0.w), a3); den += x0;
    a0 = fmaf(x1, b2f(q1.x), a0); a1 = fmaf(x1, b2f(q1.y), a1);
    a2 = fmaf(x1, b2f(q1.z), a2); a3 = fmaf(x1, b2f(q1.w), a3); den += x1;
    a0 = fmaf(x2, b2f(q2.x), a0); a1 = fmaf(x2, b2f(q2.y), a1);
    a2 = fmaf(x2, b2f(q2.z), a2); a3 = fmaf(x2, b2f(q2.w), a3); den += x2;
    a0 = fmaf(x3, b2f(q3.x), a0); a1 = fmaf(x3, b2f(q3.y), a1);
    a2 = fmaf(x3, b2f(q3.z), a2); a3 = fmaf(x3, b2f(q3.w), a3); den += x3;
  }
  for (; i < end; ++i) {
    int e = ebuf[i];
    float ex = expf(logits[e] - smax);
    ushort4 q = *reinterpret_cast<const ushort4*>(queries + (size_t)e * D + cg);
    a0 = fmaf(ex, b2f(q.x), a0); a1 = fmaf(ex, b2f(q.y), a1);
    a2 = fmaf(ex, b2f(q.z), a2); a3 = fmaf(ex, b2f(q.w), a3);
    den += ex;
  }

  float inv = 1.f / (den + 1e-10f);
  float4 v;
  v.x = a0 * inv; v.y = a1 * inv; v.z = a2 * inv; v.w = a3 * inv;
  v.x = v.x > 0.f ? v.x : 0.01f * v.x;
  v.y = v.y > 0.f ? v.y : 0.01f * v.y;
  v.z = v.z > 0.f ? v.z : 0.01f * v.z;
  v.w = v.w > 0.f ? v.w : 0.01f * v.w;
  *reinterpret_cast<float4*>(out + (size_t)node * D + cg) = v;
}

extern "C" void kernel_launch(void* const* d_in, const int* in_sizes, int n_in,
                              void* d_out, int out_size, void* d_ws, size_t ws_size,
                              hipStream_t stream) {
  const float* nodes  = (const float*)d_in[0];
  const int*   eidx   = (const int*)d_in[1];
  const float* efeat  = (const float*)d_in[2];
  const float* Wq     = (const float*)d_in[3];
  const float* bq     = (const float*)d_in[4];
  const float* W1     = (const float*)d_in[5];
  const float* b1     = (const float*)d_in[6];
  const float* gamma_ = (const float*)d_in[7];
  const float* beta_  = (const float*)d_in[8];
  const float* W2     = (const float*)d_in[9];
  const float* b2     = (const float*)d_in[10];
  const int* senders   = eidx;
  const int* receivers = eidx + NE;

  // ws layout (pad before ebuf keeps Wqt/W1t/queries 16B-aligned)
  float* ws       = (float*)d_ws;
  float* logits   = ws;                      // NE f32
  float* seg_max  = ws + NE;                 // NN f32
  int*   deg      = (int*)(seg_max + NN);    // NN
  int*   offs     = deg + NN;                // NN+1
  int*   cursor   = offs + NN + 1;           // NN
  int*   bsum     = cursor + NN;             // 256
  int*   bpre     = bsum + 256;              // 256
  int*   ebuf     = bpre + 256 + 3;          // NE
  ushort* Wqt     = (ushort*)(ebuf + NE);    // 128*320, 16B-aligned
  ushort* W1t     = Wqt + D * IN_DIM;        // 128*320, 16B-aligned
  ushort* queries = W1t + D * IN_DIM;        // NE*128 bf16, 16B-aligned

  hipMemsetAsync(seg_max, 0, NN * sizeof(float), stream);
  hipMemsetAsync(deg, 0, NN * sizeof(int), stream);

  k_wconv<<<(D * IN_DIM + 255) / 256, 256, 0, stream>>>(Wq, W1, Wqt, W1t);

  // counting sort + canonical order
  k_hist<<<(NE + 255) / 256, 256, 0, stream>>>(receivers, deg);
  k_scan1<<<NB, 256, 0, stream>>>(deg, bsum);
  k_scan2<<<1, 256, 0, stream>>>(bsum, bpre, offs);
  k_scan3<<<NB, 256, 0, stream>>>(deg, bpre, offs, cursor);
  k_bucket<<<(NE + 255) / 256, 256, 0, stream>>>(receivers, cursor, ebuf);
  k_bsort<<<NB, 256, 0, stream>>>(offs, ebuf);

  // queries + logits + seg_max
  k_fused<<<PGRID, 256, 0, stream>>>(nodes, senders, receivers, efeat,
                                     Wqt, bq, W1t, b1, gamma_, beta_, W2, b2,
                                     queries, logits, seg_max);

  // gather-side softmax + weighted sum + leaky relu
  k_out<<<(NN + 7) / 8, 256, 0, stream>>>(offs, ebuf, logits, seg_max,
                                          queries, (float*)d_out);
}

// Round 13
// 525.897 us; speedup vs baseline: 1.2069x; 1.0033x over previous
//
#include <hip/hip_runtime.h>
#include <hip/hip_bf16.h>

#define NN 50000
#define NE 800000
#define D 128
#define ED 64
#define IN_DIM 320
#define MB 64            // edges per tile
#define KP 328           // padded LDS row (ushorts)
#define NT (NE / MB)     // 12500 tiles
#define PGRID 512        // 2 blocks/CU * 256 CU — tripwire-passing config
#define NB ((NN + 255) / 256)   // 196 scan blocks

typedef short short8 __attribute__((ext_vector_type(8)));
typedef float f32x4 __attribute__((ext_vector_type(4)));

__device__ __forceinline__ ushort f2b(float f) {
  __hip_bfloat16 h = __float2bfloat16(f);
  return *reinterpret_cast<ushort*>(&h);
}
__device__ __forceinline__ float b2f(ushort u) {
  return __uint_as_float(((uint)u) << 16);
}
__device__ __forceinline__ ushort4 c4(float4 v) {
  ushort4 u; u.x = f2b(v.x); u.y = f2b(v.y); u.z = f2b(v.z); u.w = f2b(v.w);
  return u;
}

// gather one tile's x into bf16 registers, edges taken in BUCKET order via
// eid[] (receiver-sorted): consecutive edges share receivers -> nr row hits
// L1/L2 instead of L3/HBM. 4 threads per edge, 20 x ushort4.
__device__ __forceinline__ void gather_regs(
    ushort4 g[20], const int* __restrict__ eid,
    const int* __restrict__ senders, const int* __restrict__ receivers,
    const float* __restrict__ nodes, const float* __restrict__ efeat, int tid)
{
  const int e = tid >> 2, p = tid & 3;
  const int ge = eid[e];
  const float* ns = nodes + (size_t)senders[ge] * D;
  const float* nr = nodes + (size_t)receivers[ge] * D;
  const float* ef = efeat + (size_t)ge * ED;
#pragma unroll
  for (int i = 0; i < 8; ++i) g[i] = c4(*(const float4*)(ns + (p + 4 * i) * 4));
#pragma unroll
  for (int i = 0; i < 8; ++i) g[8 + i] = c4(*(const float4*)(nr + (p + 4 * i) * 4));
#pragma unroll
  for (int i = 0; i < 4; ++i) g[16 + i] = c4(*(const float4*)(ef + (p + 4 * i) * 4));
}

__device__ __forceinline__ void write_xs(
    ushort xs[MB][KP], const ushort4 g[20], int tid)
{
  const int e = tid >> 2, p = tid & 3;
#pragma unroll
  for (int i = 0; i < 8; ++i)
    *reinterpret_cast<ushort4*>(&xs[e][(p + 4 * i) * 4]) = g[i];
#pragma unroll
  for (int i = 0; i < 8; ++i)
    *reinterpret_cast<ushort4*>(&xs[e][128 + (p + 4 * i) * 4]) = g[8 + i];
#pragma unroll
  for (int i = 0; i < 4; ++i)
    *reinterpret_cast<ushort4*>(&xs[e][256 + (p + 4 * i) * 4]) = g[16 + i];
}

// ---------------- weight transpose + bf16 convert ---------------------------
__global__ __launch_bounds__(256) void k_wconv(
    const float* __restrict__ Wq, const float* __restrict__ W1,
    ushort* __restrict__ Wqt, ushort* __restrict__ W1t)
{
  int i = blockIdx.x * 256 + threadIdx.x;
  if (i < D * IN_DIM) {
    int n = i / IN_DIM, k = i - n * IN_DIM;
    Wqt[i] = f2b(Wq[k * D + n]);
    W1t[i] = f2b(W1[k * D + n]);
  }
}

// ---------------- pass 1: queries (bf16,+bq) + logits + seg_max -------------
// Round-12 kernel, processing edges in bucket order: gathers via ebuf[]
// (receiver-local reads), queries/logits written SEQUENTIALLY at bucket
// positions -> k_out streams with no indirection.
__global__ __launch_bounds__(256, 2) void k_fused(
    const float* __restrict__ nodes,
    const int* __restrict__ senders, const int* __restrict__ receivers,
    const float* __restrict__ efeat, const int* __restrict__ ebuf,
    const ushort* __restrict__ Wqt, const float* __restrict__ bq,
    const ushort* __restrict__ W1t, const float* __restrict__ b1,
    const float* __restrict__ gamma_, const float* __restrict__ beta_,
    const float* __restrict__ W2, const float* __restrict__ b2,
    ushort* __restrict__ queries, float* __restrict__ logits,
    float* __restrict__ seg_max)
{
  __shared__ ushort xs[MB][KP];
  __shared__ float red[MB][4][3];
  const int tid = threadIdx.x;
  const int w = tid >> 6, l = tid & 63, lr = l & 15, lg = l >> 4;
  const int n0 = 32 * w + lr, n1 = 32 * w + 16 + lr;

  const float b1a = b1[n0], b1b = b1[n1];
  const float g0 = gamma_[n0], g1 = gamma_[n1];
  const float be0 = beta_[n0], be1 = beta_[n1];
  const float w20 = W2[n0], w21 = W2[n1];
  const float bq0 = bq[n0], bq1 = bq[n1];
  const float b2s = b2[0];
  const float wg0 = w20 * g0, wg1 = w21 * g1;

  // tile-invariant: S1=sum(w2*g), B2t=sum(w2*beta)+b2 (0.25: cols counted 4x)
  {
    float p1 = wg0 + wg1;
    float p2 = w20 * be0 + w21 * be1;
#pragma unroll
    for (int off = 1; off < 64; off <<= 1) {
      p1 += __shfl_xor(p1, off);
      p2 += __shfl_xor(p2, off);
    }
    if (l == 0) { red[0][w][0] = p1; red[0][w][1] = p2; }
  }
  __syncthreads();
  const float S1  = 0.25f * (red[0][0][0] + red[0][1][0] + red[0][2][0] + red[0][3][0]);
  const float B2t = 0.25f * (red[0][0][1] + red[0][1][1] + red[0][2][1] + red[0][3][1]) + b2s;

  int tile = blockIdx.x;
  ushort4 g[20];
  gather_regs(g, ebuf + tile * MB, senders, receivers, nodes, efeat, tid);

  while (tile < NT) {
    const int e0 = tile * MB;
    write_xs(xs, g, tid);
    __syncthreads();                                   // (A) xs ready

    // q-GEMM: Wq streamed from L2 (issued BEFORE prefetch gathers)
    f32x4 aq[4][2] = {};
#pragma unroll 2
    for (int ks = 0; ks < 10; ++ks) {
      short8 Q0 = *reinterpret_cast<const short8*>(Wqt + n0 * IN_DIM + ks * 32 + lg * 8);
      short8 Q1 = *reinterpret_cast<const short8*>(Wqt + n1 * IN_DIM + ks * 32 + lg * 8);
      short8 A[4];
#pragma unroll
      for (int mt = 0; mt < 4; ++mt)
        A[mt] = *reinterpret_cast<const short8*>(&xs[mt * 16 + lr][ks * 32 + lg * 8]);
#pragma unroll
      for (int mt = 0; mt < 4; ++mt) {
        aq[mt][0] = __builtin_amdgcn_mfma_f32_16x16x32_bf16(A[mt], Q0, aq[mt][0], 0, 0, 0);
        aq[mt][1] = __builtin_amdgcn_mfma_f32_16x16x32_bf16(A[mt], Q1, aq[mt][1], 0, 0, 0);
      }
    }
    // store queries (+bq) sequentially at bucket positions
#pragma unroll
    for (int mt = 0; mt < 4; ++mt)
#pragma unroll
      for (int r = 0; r < 4; ++r) {
        int row = mt * 16 + lg * 4 + r;
        queries[(size_t)(e0 + row) * D + n0] = f2b(aq[mt][0][r] + bq0);
        queries[(size_t)(e0 + row) * D + n1] = f2b(aq[mt][1][r] + bq1);
      }

    // prefetch next tile's gathers (bucket order)
    const int nxt = tile + PGRID;
    if (nxt < NT)
      gather_regs(g, ebuf + nxt * MB, senders, receivers, nodes, efeat, tid);

    // h-GEMM: W1 streamed
    f32x4 ah[4][2] = {};
#pragma unroll
    for (int ks = 0; ks < 10; ++ks) {
      short8 Y0 = *reinterpret_cast<const short8*>(W1t + n0 * IN_DIM + ks * 32 + lg * 8);
      short8 Y1 = *reinterpret_cast<const short8*>(W1t + n1 * IN_DIM + ks * 32 + lg * 8);
      short8 A[4];
#pragma unroll
      for (int mt = 0; mt < 4; ++mt)
        A[mt] = *reinterpret_cast<const short8*>(&xs[mt * 16 + lr][ks * 32 + lg * 8]);
#pragma unroll
      for (int mt = 0; mt < 4; ++mt) {
        ah[mt][0] = __builtin_amdgcn_mfma_f32_16x16x32_bf16(A[mt], Y0, ah[mt][0], 0, 0, 0);
        ah[mt][1] = __builtin_amdgcn_mfma_f32_16x16x32_bf16(A[mt], Y1, ah[mt][1], 0, 0, 0);
      }
    }

    // relu + fused LN/dot partials (16-lane reduce: each col once per group)
#pragma unroll
    for (int mt = 0; mt < 4; ++mt)
#pragma unroll
      for (int r = 0; r < 4; ++r) {
        float h0 = fmaxf(ah[mt][0][r] + b1a, 0.f);
        float h1 = fmaxf(ah[mt][1][r] + b1b, 0.f);
        float s = h0 + h1;
        float q = h0 * h0 + h1 * h1;
        float t = h0 * wg0 + h1 * wg1;
#pragma unroll
        for (int off = 1; off < 16; off <<= 1) {
          s += __shfl_xor(s, off);
          q += __shfl_xor(q, off);
          t += __shfl_xor(t, off);
        }
        if (lr == mt * 4 + r) {
          int row = mt * 16 + lg * 4 + r;
          red[row][w][0] = s;
          red[row][w][1] = q;
          red[row][w][2] = t;
        }
      }
    __syncthreads();                                   // (B) red ready
    if (tid < MB) {
      float s = red[tid][0][0] + red[tid][1][0] + red[tid][2][0] + red[tid][3][0];
      float q = red[tid][0][1] + red[tid][1][1] + red[tid][2][1] + red[tid][3][1];
      float t = red[tid][0][2] + red[tid][1][2] + red[tid][2][2] + red[tid][3][2];
      float mu = s * (1.f / 128.f);
      float var = fmaxf(q * (1.f / 128.f) - mu * mu, 0.f);
      float rs = rsqrtf(var + 1e-5f);
      float logit = fmaxf(rs * (t - mu * S1) + B2t, 0.f);
      logits[e0 + tid] = logit;                        // bucket position
      int ge = ebuf[e0 + tid];
      atomicMax((int*)&seg_max[receivers[ge]], __float_as_int(logit));
    }
    tile = nxt;
  }
}

// ---------------- counting sort by receiver ---------------------------------
__global__ __launch_bounds__(256) void k_hist(
    const int* __restrict__ receivers, int* __restrict__ deg)
{
  int e = blockIdx.x * 256 + threadIdx.x;
  if (e < NE) atomicAdd(&deg[receivers[e]], 1);
}

__global__ __launch_bounds__(256) void k_scan1(
    const int* __restrict__ deg, int* __restrict__ bsum)
{
  __shared__ int buf[256];
  int i = blockIdx.x * 256 + threadIdx.x;
  int v = (i < NN) ? deg[i] : 0;
  buf[threadIdx.x] = v;
  __syncthreads();
  for (int off = 128; off > 0; off >>= 1) {
    if (threadIdx.x < off) buf[threadIdx.x] += buf[threadIdx.x + off];
    __syncthreads();
  }
  if (threadIdx.x == 0) bsum[blockIdx.x] = buf[0];
}

__global__ __launch_bounds__(256) void k_scan2(
    const int* __restrict__ bsum, int* __restrict__ bpre, int* __restrict__ offs)
{
  __shared__ int buf[256];
  int t = threadIdx.x;
  int v = (t < NB) ? bsum[t] : 0;
  buf[t] = v;
  __syncthreads();
  for (int off = 1; off < 256; off <<= 1) {
    int x = (t >= off) ? buf[t - off] : 0;
    __syncthreads();
    buf[t] += x;
    __syncthreads();
  }
  if (t < NB) bpre[t] = buf[t] - v;          // exclusive
  if (t == 0) offs[NN] = NE;                  // sentinel
}

__global__ __launch_bounds__(256) void k_scan3(
    const int* __restrict__ deg, const int* __restrict__ bpre,
    int* __restrict__ offs, int* __restrict__ cursor)
{
  __shared__ int buf[256];
  int t = threadIdx.x;
  int i = blockIdx.x * 256 + t;
  int v = (i < NN) ? deg[i] : 0;
  buf[t] = v;
  __syncthreads();
  for (int off = 1; off < 256; off <<= 1) {
    int x = (t >= off) ? buf[t - off] : 0;
    __syncthreads();
    buf[t] += x;
    __syncthreads();
  }
  if (i < NN) {
    int o = bpre[blockIdx.x] + buf[t] - v;
    offs[i] = o;
    cursor[i] = o;
  }
}

__global__ __launch_bounds__(256) void k_bucket(
    const int* __restrict__ receivers, int* __restrict__ cursor,
    int* __restrict__ ebuf)
{
  int e = blockIdx.x * 256 + threadIdx.x;
  if (e < NE) {
    int pos = atomicAdd(&cursor[receivers[e]], 1);
    ebuf[pos] = e;
  }
}

// Canonicalize bucket order (atomicAdd placement is scheduling-dependent):
// insertion-sort each node's segment so ebuf is a pure function of inputs.
__global__ __launch_bounds__(256) void k_bsort(
    const int* __restrict__ offs, int* __restrict__ ebuf)
{
  int node = blockIdx.x * 256 + threadIdx.x;
  if (node >= NN) return;
  const int beg = offs[node], end = offs[node + 1];
  for (int i = beg + 1; i < end; ++i) {
    int v = ebuf[i];
    int j = i - 1;
    while (j >= beg && ebuf[j] > v) { ebuf[j + 1] = ebuf[j]; --j; }
    ebuf[j + 1] = v;
  }
}

// ---------------- gather-side output: fully streaming -----------------------
// queries/logits are bucket-ordered -> rows beg..end contiguous; same 4-deep
// batching and strict ascending-i accumulation as round 12 (tripwire-green).
__global__ __launch_bounds__(256) void k_out(
    const int* __restrict__ offs, const float* __restrict__ logits,
    const float* __restrict__ seg_max, const ushort* __restrict__ queries,
    float* __restrict__ out)
{
  int node = blockIdx.x * 8 + (threadIdx.x >> 5);
  if (node >= NN) return;
  const int cg = (threadIdx.x & 31) * 4;      // 4 columns per lane
  const int beg = offs[node], end = offs[node + 1];
  const float smax = seg_max[node];
  float a0 = 0.f, a1 = 0.f, a2 = 0.f, a3 = 0.f, den = 0.f;

  int i = beg;
  for (; i + 4 <= end; i += 4) {
    float l0 = logits[i], l1 = logits[i + 1], l2 = logits[i + 2], l3 = logits[i + 3];
    ushort4 q0 = *reinterpret_cast<const ushort4*>(queries + (size_t)i * D + cg);
    ushort4 q1 = *reinterpret_cast<const ushort4*>(queries + (size_t)(i + 1) * D + cg);
    ushort4 q2 = *reinterpret_cast<const ushort4*>(queries + (size_t)(i + 2) * D + cg);
    ushort4 q3 = *reinterpret_cast<const ushort4*>(queries + (size_t)(i + 3) * D + cg);
    float x0 = expf(l0 - smax), x1 = expf(l1 - smax);
    float x2 = expf(l2 - smax), x3 = expf(l3 - smax);
    a0 = fmaf(x0, b2f(q0.x), a0); a1 = fmaf(x0, b2f(q0.y), a1);
    a2 = fmaf(x0, b2f(q0.z), a2); a3 = fmaf(x0, b2f(q0.w), a3); den += x0;
    a0 = fmaf(x1, b2f(q1.x), a0); a1 = fmaf(x1, b2f(q1.y), a1);
    a2 = fmaf(x1, b2f(q1.z), a2); a3 = fmaf(x1, b2f(q1.w), a3); den += x1;
    a0 = fmaf(x2, b2f(q2.x), a0); a1 = fmaf(x2, b2f(q2.y), a1);
    a2 = fmaf(x2, b2f(q2.z), a2); a3 = fmaf(x2, b2f(q2.w), a3); den += x2;
    a0 = fmaf(x3, b2f(q3.x), a0); a1 = fmaf(x3, b2f(q3.y), a1);
    a2 = fmaf(x3, b2f(q3.z), a2); a3 = fmaf(x3, b2f(q3.w), a3); den += x3;
  }
  for (; i < end; ++i) {
    float ex = expf(logits[i] - smax);
    ushort4 q = *reinterpret_cast<const ushort4*>(queries + (size_t)i * D + cg);
    a0 = fmaf(ex, b2f(q.x), a0); a1 = fmaf(ex, b2f(q.y), a1);
    a2 = fmaf(ex, b2f(q.z), a2); a3 = fmaf(ex, b2f(q.w), a3);
    den += ex;
  }

  float inv = 1.f / (den + 1e-10f);
  float4 v;
  v.x = a0 * inv; v.y = a1 * inv; v.z = a2 * inv; v.w = a3 * inv;
  v.x = v.x > 0.f ? v.x : 0.01f * v.x;
  v.y = v.y > 0.f ? v.y : 0.01f * v.y;
  v.z = v.z > 0.f ? v.z : 0.01f * v.z;
  v.w = v.w > 0.f ? v.w : 0.01f * v.w;
  *reinterpret_cast<float4*>(out + (size_t)node * D + cg) = v;
}

extern "C" void kernel_launch(void* const* d_in, const int* in_sizes, int n_in,
                              void* d_out, int out_size, void* d_ws, size_t ws_size,
                              hipStream_t stream) {
  const float* nodes  = (const float*)d_in[0];
  const int*   eidx   = (const int*)d_in[1];
  const float* efeat  = (const float*)d_in[2];
  const float* Wq     = (const float*)d_in[3];
  const float* bq     = (const float*)d_in[4];
  const float* W1     = (const float*)d_in[5];
  const float* b1     = (const float*)d_in[6];
  const float* gamma_ = (const float*)d_in[7];
  const float* beta_  = (const float*)d_in[8];
  const float* W2     = (const float*)d_in[9];
  const float* b2     = (const float*)d_in[10];
  const int* senders   = eidx;
  const int* receivers = eidx + NE;

  // ws layout (pad before ebuf keeps Wqt/W1t/queries 16B-aligned)
  float* ws       = (float*)d_ws;
  float* logits   = ws;                      // NE f32 (bucket-ordered)
  float* seg_max  = ws + NE;                 // NN f32
  int*   deg      = (int*)(seg_max + NN);    // NN
  int*   offs     = deg + NN;                // NN+1
  int*   cursor   = offs + NN + 1;           // NN
  int*   bsum     = cursor + NN;             // 256
  int*   bpre     = bsum + 256;              // 256
  int*   ebuf     = bpre + 256 + 3;          // NE
  ushort* Wqt     = (ushort*)(ebuf + NE);    // 128*320, 16B-aligned
  ushort* W1t     = Wqt + D * IN_DIM;        // 128*320, 16B-aligned
  ushort* queries = W1t + D * IN_DIM;        // NE*128 bf16 (bucket-ordered)

  hipMemsetAsync(seg_max, 0, NN * sizeof(float), stream);
  hipMemsetAsync(deg, 0, NN * sizeof(int), stream);

  k_wconv<<<(D * IN_DIM + 255) / 256, 256, 0, stream>>>(Wq, W1, Wqt, W1t);

  // counting sort + canonical order (must precede k_fused: it reads ebuf)
  k_hist<<<(NE + 255) / 256, 256, 0, stream>>>(receivers, deg);
  k_scan1<<<NB, 256, 0, stream>>>(deg, bsum);
  k_scan2<<<1, 256, 0, stream>>>(bsum, bpre, offs);
  k_scan3<<<NB, 256, 0, stream>>>(deg, bpre, offs, cursor);
  k_bucket<<<(NE + 255) / 256, 256, 0, stream>>>(receivers, cursor, ebuf);
  k_bsort<<<NB, 256, 0, stream>>>(offs, ebuf);

  // queries + logits (bucket-ordered) + seg_max
  k_fused<<<PGRID, 256, 0, stream>>>(nodes, senders, receivers, efeat, ebuf,
                                     Wqt, bq, W1t, b1, gamma_, beta_, W2, b2,
                                     queries, logits, seg_max);

  // gather-side softmax + weighted sum + leaky relu (fully streaming)
  k_out<<<(NN + 7) / 8, 256, 0, stream>>>(offs, logits, seg_max,
                                          queries, (float*)d_out);
}